// Round 14
// baseline (3946.835 us; speedup 1.0000x reference)
//
#include <hip/hip_runtime.h>
#include <hip/hip_bf16.h>

#define HH 512
#define WW 512
#define CIN 256
#define COUT 256
#define NPTS 65536
#define PW 514
#define NPIX (PW * PW)
#define NKT 72                       // 72 k32-tiles = 4 chunks x 18 tiles
#define TICKETS_PER_CHUNK 4096
#define TOTAL_TICKETS 16384

typedef __bf16 bf16x8 __attribute__((ext_vector_type(8)));
typedef float f32x16 __attribute__((ext_vector_type(16)));
typedef unsigned short us8 __attribute__((ext_vector_type(8)));

static __device__ __forceinline__ unsigned short f2bf(float f) {
  unsigned u = __builtin_bit_cast(unsigned, f);
  unsigned r = u + 0x7fffu + ((u >> 16) & 1u);
  return (unsigned short)(r >> 16);
}

// A2 frag-contiguous layout (r12-verified concept, re-banded):
// i = kt*8192 + band*2048 + frag*512 + l*8 + j ; frag = mt*2+kg.
// row = band*64 + mt*32 + (l&31);
// K-order is ci-chunk-major: kt -> chunk=kt/18, r=kt%18, tap=r>>1, cihalf=r&1;
// ci = chunk*64 + cihalf*32 + kg*16 + (l>>5)*8 + j; element = w[row][ci*9+tap].
// A wave reading A2 + kt*8192 + band*2048 + f*512 + lane*8 gets one coalesced
// 1KB MFMA A-fragment.
__global__ __launch_bounds__(256) void prep_weight(const float* __restrict__ w,
                                                   unsigned short* __restrict__ A2) {
  int i = blockIdx.x * 256 + threadIdx.x;       // 72*8192 = 589824 total
  int kt   = i >> 13;
  int band = (i >> 11) & 3;
  int frag = (i >> 9) & 3;
  int l    = (i >> 3) & 63;
  int j    = i & 7;
  int mt = frag >> 1, kg = frag & 1;
  int row = band * 64 + mt * 32 + (l & 31);
  int chunk = kt / 18, r = kt % 18;
  int tap = r >> 1, cihalf = r & 1;
  int ci = chunk * 64 + cihalf * 32 + kg * 16 + (l >> 5) * 8 + j;
  A2[i] = f2bf(__builtin_nontemporal_load(&w[row * 2304 + ci * 9 + tap]));
}

// Zero the border ring of the padded (514x514) bf16 feature image.
__global__ __launch_bounds__(256) void border_zero(unsigned short* __restrict__ Ft) {
  int g = blockIdx.x * 256 + threadIdx.x;
  if (g >= 2052 * 32) return;
  int p = g >> 5, c = g & 31;
  int py, px;
  if (p < 514)        { py = 0;        px = p; }
  else if (p < 1028)  { py = 513;      px = p - 514; }
  else if (p < 1540)  { py = p - 1027; px = 0; }
  else                { py = p - 1539; px = 513; }
  *(us8*)&Ft[((size_t)py * PW + px) * 256 + c * 8] = (us8){0, 0, 0, 0, 0, 0, 0, 0};
}

// Fused transpose+gemm. 1024 blocks x 256 thr (4 independent waves, NO LDS,
// NO barriers). Wave = 64 rows x 64 cols, full K. K is ci-chunk-major; before
// consuming chunk c a wave gates on done[c]==4096, SELF-HELPING by claiming
// transpose tickets (64px x 64ci each) while it waits. Monotonic global
// tickets => progress guaranteed at any residency (no deadlock possible).
// ctrl[0]=ticket, ctrl[1..4]=done[chunk] (memset to 0 per launch).
__global__ __launch_bounds__(256, 4) void fused_gemm(
    const unsigned short* __restrict__ A2,
    unsigned short* __restrict__ Ft,          // [514*514][256] bf16 padded
    const float* __restrict__ feat,           // [256][512][512] f32
    const int* __restrict__ hidx,
    const int* __restrict__ widx,
    float* __restrict__ out,
    unsigned int* __restrict__ ctrl) {
  int tid = threadIdx.x, lane = tid & 63, wv = tid >> 6;
  int n0 = blockIdx.x << 6;                   // 64 cols per block

  // Per-lane B fragment bases (k-mapping mirrors the r9-verified LDB):
  // element k_local = kg*16 + (lane>>5)*8 + j  <->  byte kg*32 + (lane>>5)*16.
  int colA = n0 + (lane & 31);
  long pixA = (long)hidx[colA] * PW + widx[colA];
  long pixB = (long)hidx[colA + 32] * PW + widx[colA + 32];
  const char* pB0 = (const char*)Ft + pixA * 512 + ((lane >> 5) << 4);
  const char* pB1 = (const char*)Ft + pixB * 512 + ((lane >> 5) << 4);
  const unsigned short* pA = A2 + wv * 2048 + lane * 8;

  f32x16 acc[2][2];
#pragma unroll
  for (int mt = 0; mt < 2; ++mt)
#pragma unroll
    for (int nt = 0; nt < 2; ++nt)
      acc[mt][nt] = (f32x16)(0.f);

#define MF(x_, y_, z_) __builtin_amdgcn_mfma_f32_32x32x16_bf16(x_, y_, z_, 0, 0, 0)

  for (int c = 0; c < 4; ++c) {
    // ---- gate on chunk c, self-helping with transpose tickets ----
    for (;;) {
      unsigned d0 = 0;
      if (lane == 0) d0 = atomicAdd(&ctrl[1 + c], 0u);
      d0 = (unsigned)__builtin_amdgcn_readfirstlane((int)d0);
      if (d0 >= (unsigned)TICKETS_PER_CHUNK) break;
      unsigned t = 0xffffffffu;
      if (lane == 0) t = atomicAdd(&ctrl[0], 1u);
      t = (unsigned)__builtin_amdgcn_readfirstlane((int)t);
      if (t < (unsigned)TOTAL_TICKETS) {
        int tc = t >> 12, g = t & 4095;       // chunk, 64-pixel group (one row)
        int y = g >> 3, x0 = (g & 7) << 6;
        const float* src = feat + (size_t)tc * 64 * 262144 + y * 512 + x0 + lane;
        unsigned short* dst =
            Ft + ((size_t)(y + 1) * PW + x0 + 1 + lane) * 256 + tc * 64;
#pragma unroll
        for (int s = 0; s < 8; ++s) {
          us8 v;
#pragma unroll
          for (int j = 0; j < 8; ++j)
            v[j] = f2bf(__builtin_nontemporal_load(src + (size_t)(s * 8 + j) * 262144));
          *(us8*)(dst + s * 8) = v;           // plain store: L2-combined 128B/pixel
        }
        __threadfence();                      // release: Ft writes -> visible
        if (lane == 0) atomicAdd(&ctrl[1 + tc], 1u);
      } else {
        __builtin_amdgcn_s_sleep(16);
      }
    }
    __threadfence();                          // acquire for Ft reads

    // ---- 18 k32-tiles of chunk c (tap-major within chunk) ----
    const unsigned short* pAc = pA + (size_t)c * 18 * 8192;
    int cbase = c * 128;                      // chunk byte offset within pixel
#pragma unroll
    for (int r = 0; r < 18; ++r) {
      const int tap = r >> 1;
      const int off = ((tap / 3) * PW + (tap % 3)) * 512 + cbase + (r & 1) * 64;
      bf16x8 a0 = *(const bf16x8*)&pAc[r * 8192];          // mt0 kg0
      bf16x8 a1 = *(const bf16x8*)&pAc[r * 8192 + 512];    // mt0 kg1
      bf16x8 a2 = *(const bf16x8*)&pAc[r * 8192 + 1024];   // mt1 kg0
      bf16x8 a3 = *(const bf16x8*)&pAc[r * 8192 + 1536];   // mt1 kg1
      bf16x8 b00 = *(const bf16x8*)(pB0 + off);            // nt0 kg0
      bf16x8 b01 = *(const bf16x8*)(pB0 + off + 32);       // nt0 kg1
      bf16x8 b10 = *(const bf16x8*)(pB1 + off);            // nt1 kg0
      bf16x8 b11 = *(const bf16x8*)(pB1 + off + 32);       // nt1 kg1
      __builtin_amdgcn_s_setprio(1);
      acc[0][0] = MF(a0, b00, acc[0][0]);
      acc[0][1] = MF(a0, b10, acc[0][1]);
      acc[1][0] = MF(a2, b00, acc[1][0]);
      acc[1][1] = MF(a2, b10, acc[1][1]);
      acc[0][0] = MF(a1, b01, acc[0][0]);
      acc[0][1] = MF(a1, b11, acc[0][1]);
      acc[1][0] = MF(a3, b01, acc[1][0]);
      acc[1][1] = MF(a3, b11, acc[1][1]);
      __builtin_amdgcn_s_setprio(0);
    }
  }
#undef MF

  // Epilogue (verified map): col = lane&31, row = (r&3)+8*(r>>2)+4*(lane>>5).
  int colb = n0 + (lane & 31);
  int rb = wv * 64 + ((lane >> 5) << 2);
#pragma unroll
  for (int mt = 0; mt < 2; ++mt)
#pragma unroll
    for (int nt = 0; nt < 2; ++nt)
#pragma unroll
      for (int r = 0; r < 16; ++r) {
        int row = rb + mt * 32 + (r & 3) + ((r >> 2) << 3);
        __builtin_nontemporal_store(acc[mt][nt][r],
                                    &out[(size_t)row * NPTS + colb + nt * 32]);
      }
}

// Safety-net path if workspace is too small: direct conv, fp32.
__global__ __launch_bounds__(256) void naive_conv(const float* __restrict__ f,
                                                  const float* __restrict__ w,
                                                  const int* __restrict__ hi,
                                                  const int* __restrict__ wi,
                                                  float* __restrict__ out) {
  int idx = blockIdx.x * 256 + threadIdx.x;
  int n = idx & (NPTS - 1);
  int co = idx >> 16;
  int bh = hi[n] - 1;
  int bw = wi[n] - 1;
  float acc = 0.f;
  for (int ci = 0; ci < CIN; ++ci) {
    const float* fc = f + (size_t)ci * 262144;
    const float* wc = w + (size_t)co * 2304 + ci * 9;
#pragma unroll
    for (int t = 0; t < 9; ++t) {
      int y = bh + t / 3, x = bw + t % 3;
      float v = (y >= 0 && y < 512 && x >= 0 && x < 512) ? fc[y * 512 + x] : 0.f;
      acc += wc[t] * v;
    }
  }
  out[(size_t)co * NPTS + n] = acc;
}

extern "C" void kernel_launch(void* const* d_in, const int* in_sizes, int n_in,
                              void* d_out, int out_size, void* d_ws, size_t ws_size,
                              hipStream_t stream) {
  const float* feature = (const float*)d_in[0];
  const float* weight  = (const float*)d_in[1];
  const int* hidx      = (const int*)d_in[2];
  const int* widx      = (const int*)d_in[3];
  float* out           = (float*)d_out;

  const size_t FT_OFF = 2ull * 1024 * 1024;
  const size_t FT_BYTES = (size_t)NPIX * 256 * 2;   // ~135 MiB
  const size_t CTRL_OFF = 160ull * 1024 * 1024;
  const size_t NEED = CTRL_OFF + 4096;

  if (ws_size >= NEED) {
    unsigned short* A2 = (unsigned short*)d_ws;     // 1.125 MiB
    unsigned short* Ft = (unsigned short*)((char*)d_ws + FT_OFF);
    unsigned int* ctrl = (unsigned int*)((char*)d_ws + CTRL_OFF);
    prep_weight<<<(NKT * 8192) / 256, 256, 0, stream>>>(weight, A2);
    border_zero<<<(2052 * 32 + 255) / 256, 256, 0, stream>>>(Ft);
    hipMemsetAsync(ctrl, 0, 32, stream);
    fused_gemm<<<NPTS / 64, 256, 0, stream>>>(A2, Ft, feature, hidx, widx, out, ctrl);
  } else {
    naive_conv<<<(COUT * NPTS) / 256, 256, 0, stream>>>(feature, weight, hidx, widx, out);
  }
}

// Round 15
// 159.933 us; speedup vs baseline: 24.6780x; 24.6780x over previous
//
#include <hip/hip_runtime.h>
#include <hip/hip_bf16.h>

#define HH 512
#define WW 512
#define CIN 256
#define COUT 256
#define NPTS 65536
#define PW 514
#define NPIX (PW * PW)
#define NKT 72                      // K tiles of 32; 36 B pair-stages of 64 ci

typedef __bf16 bf16x8 __attribute__((ext_vector_type(8)));
typedef float f32x16 __attribute__((ext_vector_type(16)));
typedef unsigned short us8 __attribute__((ext_vector_type(8)));

static __device__ __forceinline__ unsigned short f2bf(float f) {
  unsigned u = __builtin_bit_cast(unsigned, f);
  unsigned r = u + 0x7fffu + ((u >> 16) & 1u);
  return (unsigned short)(r >> 16);
}

static __device__ __forceinline__ void gload16(const void* g, void* l) {
  __builtin_amdgcn_global_load_lds(
      (const __attribute__((address_space(1))) unsigned int*)g,
      (__attribute__((address_space(3))) unsigned int*)l, 16, 0, 0);
}

// A layout (verified r2-r9): i = kt*8192 + o ; r = o>>5 (co),
// cp = (o>>3)&3, j = o&7, logical chunk c = cp ^ ((r>>1)&3),
// k = kt*32 + c*8 + j (k = t*256+ci). Linear 16KB DMA -> swizzled LDS tile.
__global__ __launch_bounds__(256) void prep_weight(const float* __restrict__ w,
                                                   unsigned short* __restrict__ A) {
  int i = blockIdx.x * 256 + threadIdx.x;       // 72*8192 = 589824 total
  int kt = i >> 13;
  int o  = i & 8191;
  int r  = o >> 5;
  int cp = (o >> 3) & 3;
  int j  = o & 7;
  int c  = cp ^ ((r >> 1) & 3);
  int k  = kt * 32 + c * 8 + j;
  int t  = k >> 8;
  int ci = k & 255;
  A[i] = f2bf(__builtin_nontemporal_load(&w[r * 2304 + ci * 9 + t]));
}

// Zero the border ring of the padded (514x514) bf16 feature image.
__global__ __launch_bounds__(256) void border_zero(unsigned short* __restrict__ Ft) {
  int g = blockIdx.x * 256 + threadIdx.x;
  if (g >= 2052 * 32) return;
  int p = g >> 5, c = g & 31;
  int py, px;
  if (p < 514)        { py = 0;        px = p; }
  else if (p < 1028)  { py = 513;      px = p - 514; }
  else if (p < 1540)  { py = p - 1027; px = 0; }
  else                { py = p - 1539; px = 513; }
  *(us8*)&Ft[((size_t)py * PW + px) * 256 + c * 8] = (us8){0, 0, 0, 0, 0, 0, 0, 0};
}

// Ft[((y+1)*514 + (x+1))*256 + ci] = bf16(feature[ci][y][x])
// f32 reads NONTEMPORAL (r9, verified −12 µs): keep the 256 MB stream out of
// L2/L3 so Ft stays resident for the gemm's random gathers.
__global__ __launch_bounds__(256) void transpose_feat(const float* __restrict__ f,
                                                      unsigned short* __restrict__ Ft) {
  __shared__ unsigned short lds[64 * 264];
  int pix0 = blockIdx.x * 64;
  int y = pix0 >> 9, x0 = pix0 & 511;
  int tid = threadIdx.x;
  int p = tid & 63;
  int cb = tid >> 6;
  const float* src = f + pix0 + p;
  for (int c8 = 0; c8 < 8; ++c8) {
    us8 v;
#pragma unroll
    for (int j = 0; j < 8; ++j) {
      int ci = cb * 64 + c8 * 8 + j;
      v[j] = f2bf(__builtin_nontemporal_load(&src[ci * 262144]));
    }
    *(us8*)&lds[p * 264 + cb * 64 + c8 * 8] = v;
  }
  __syncthreads();
  int cic = tid & 31;
  int pr = tid >> 5;
  for (int g = 0; g < 8; ++g) {
    int p2 = pr + g * 8;
    us8 v = *(const us8*)&lds[p2 * 264 + cic * 8];
    *(us8*)&Ft[((size_t)((y + 1) * PW + x0 + 1 + p2)) * 256 + cic * 8] = v;
  }
}

// 256x256xK gather-GEMM. B staged as 128B-per-pixel pair-granules (64 ci),
// A x3 bufs staged t+2; B-pair x3 bufs staged q+2. Uniform vmcnt(6) at every
// HEAD (ledger hand-verified incl. clamped tail). 8 waves (2M x 4N),
// wave tile 128x64, 32x32 MFMA. Output stores NONTEMPORAL.
__global__ __launch_bounds__(512, 2) void gemm_gather(
    const unsigned short* __restrict__ A,     // prep'd, swizzle baked in
    const unsigned short* __restrict__ Ft,    // [514*514][256] bf16 padded
    const int* __restrict__ hidx,
    const int* __restrict__ widx,
    float* __restrict__ out) {
  __shared__ unsigned short lds[73728];       // A: 3*8192 @0, B: 3*16384 @24576
  unsigned short* ldsB = lds + 24576;

  int tid = threadIdx.x;
  int lane = tid & 63, wv = tid >> 6;
  int wm = wv & 1, wn = wv >> 1;
  int n0 = blockIdx.x << 8;

  // B gather: pass P covers cols [P*64, P*64+64). Thread handles pixel
  // col = P*64 + (tid>>3), physical 16B chunk pc = tid&7 holding logical
  // chunk lc = pc ^ (col&7). Each pixel's 8 lanes read one contiguous
  // 128B run (permuted internally).
  int pxc = tid >> 3;                  // 0..63
  int lcB = (tid & 7) ^ (pxc & 7);
  const unsigned short *FtP0, *FtP1, *FtP2, *FtP3;
  {
    FtP0 = Ft + (long)(hidx[n0 + pxc] * PW + widx[n0 + pxc]) * 256 + lcB * 8;
    FtP1 = Ft + (long)(hidx[n0 + 64 + pxc] * PW + widx[n0 + 64 + pxc]) * 256 + lcB * 8;
    FtP2 = Ft + (long)(hidx[n0 + 128 + pxc] * PW + widx[n0 + 128 + pxc]) * 256 + lcB * 8;
    FtP3 = Ft + (long)(hidx[n0 + 192 + pxc] * PW + widx[n0 + 192 + pxc]) * 256 + lcB * 8;
  }

#define STAGE_A(t_, ab_)                                                      \
  do {                                                                        \
    const unsigned short* g_ = A + (size_t)(t_) * 8192 + tid * 8;             \
    unsigned short* l_ = lds + (ab_) * 8192 + tid * 8;                        \
    gload16(g_, l_);                                                          \
    gload16(g_ + 4096, l_ + 4096);                                            \
  } while (0)

// Pair q_: tap = q_>>2, ci0 = (q_&3)*64. 4 gloads; 128B/pixel contiguous.
#define STAGE_BP(q_, bb_)                                                     \
  do {                                                                        \
    int tap_ = (q_) >> 2;                                                     \
    long off_ = (long)((tap_ / 3) * PW + (tap_ - (tap_ / 3) * 3)) * 256 +     \
                ((q_) & 3) * 64;                                              \
    unsigned short* l_ = ldsB + (bb_) * 16384 + tid * 8;                      \
    gload16(FtP0 + off_, l_);                                                 \
    gload16(FtP1 + off_, l_ + 4096);                                          \
    gload16(FtP2 + off_, l_ + 8192);                                          \
    gload16(FtP3 + off_, l_ + 12288);                                         \
  } while (0)

#define LDA(dst, ab_, kg_, mt_)                                               \
  do {                                                                        \
    int r_ = wm * 128 + (mt_) * 32 + (lane & 31);                             \
    int c_ = ((kg_) * 2 + (lane >> 5)) ^ ((r_ >> 1) & 3);                     \
    dst = *(const bf16x8*)&lds[(ab_) * 8192 + r_ * 32 + c_ * 8];              \
  } while (0)

// B LDS: [col][chunk]: offset = col*64 + phys*8; phys = logical ^ (col&7).
// Tile parity s_ selects logical chunks s_*4..s_*4+3.
#define LDB(dst, bb_, s_, kg_, nt_)                                           \
  do {                                                                        \
    int col_ = wn * 64 + (nt_) * 32 + (lane & 31);                            \
    int ph_ = ((s_) * 4 + (kg_) * 2 + (lane >> 5)) ^ (col_ & 7);              \
    dst = *(const bf16x8*)&ldsB[(bb_) * 16384 + col_ * 64 + ph_ * 8];         \
  } while (0)

#define MFMA8(a0, a1, a2, a3, b0, b1)                                         \
  do {                                                                        \
    __builtin_amdgcn_s_setprio(1);                                            \
    acc[0][0] = __builtin_amdgcn_mfma_f32_32x32x16_bf16(a0, b0, acc[0][0], 0, 0, 0); \
    acc[0][1] = __builtin_amdgcn_mfma_f32_32x32x16_bf16(a0, b1, acc[0][1], 0, 0, 0); \
    acc[1][0] = __builtin_amdgcn_mfma_f32_32x32x16_bf16(a1, b0, acc[1][0], 0, 0, 0); \
    acc[1][1] = __builtin_amdgcn_mfma_f32_32x32x16_bf16(a1, b1, acc[1][1], 0, 0, 0); \
    acc[2][0] = __builtin_amdgcn_mfma_f32_32x32x16_bf16(a2, b0, acc[2][0], 0, 0, 0); \
    acc[2][1] = __builtin_amdgcn_mfma_f32_32x32x16_bf16(a2, b1, acc[2][1], 0, 0, 0); \
    acc[3][0] = __builtin_amdgcn_mfma_f32_32x32x16_bf16(a3, b0, acc[3][0], 0, 0, 0); \
    acc[3][1] = __builtin_amdgcn_mfma_f32_32x32x16_bf16(a3, b1, acc[3][1], 0, 0, 0); \
    __builtin_amdgcn_s_setprio(0);                                            \
  } while (0)

// Waits BEFORE barrier (r6 rule): after the barrier, all waves' DMA slices
// through the drain point are LDS-resident.
#define HEAD()                                                                \
  do {                                                                        \
    asm volatile("s_waitcnt lgkmcnt(0)" ::: "memory");                        \
    asm volatile("s_waitcnt vmcnt(6)" ::: "memory");                          \
    __builtin_amdgcn_s_barrier();                                             \
    __builtin_amdgcn_sched_barrier(0);                                        \
  } while (0)

#define TILE(ab_, bb_, s_, ...)                                               \
  do {                                                                        \
    HEAD();                                                                   \
    bf16x8 xa0, xa1, xa2, xa3, xb0, xb1, ya0, ya1, ya2, ya3, yb0, yb1;        \
    LDA(xa0, ab_, 0, 0); LDA(xa1, ab_, 0, 1); LDA(xa2, ab_, 0, 2);            \
    LDA(xa3, ab_, 0, 3); LDB(xb0, bb_, s_, 0, 0); LDB(xb1, bb_, s_, 0, 1);    \
    __VA_ARGS__;                                                              \
    LDA(ya0, ab_, 1, 0); LDA(ya1, ab_, 1, 1); LDA(ya2, ab_, 1, 2);            \
    LDA(ya3, ab_, 1, 3); LDB(yb0, bb_, s_, 1, 0); LDB(yb1, bb_, s_, 1, 1);    \
    MFMA8(xa0, xa1, xa2, xa3, xb0, xb1);                                      \
    MFMA8(ya0, ya1, ya2, ya3, yb0, yb1);                                      \
  } while (0)

  f32x16 acc[4][2];
#pragma unroll
  for (int mt = 0; mt < 4; ++mt)
#pragma unroll
    for (int nt = 0; nt < 2; ++nt)
      acc[mt][nt] = (f32x16)(0.f);

  // Prologue in ledger order: BP(0), A(0), A(1), BP(1) -> 12 loads.
  STAGE_BP(0, 0);
  STAGE_A(0, 0);
  STAGE_A(1, 1);
  STAGE_BP(1, 1);

  // Steady state (ledger verified r8): uniform vmcnt(6) at every HEAD.
  for (int P3 = 0; P3 < 12; ++P3) {
#pragma unroll
    for (int v = 0; v < 3; ++v) {
      int q = P3 * 3 + v;
      int t = 2 * q;
      TILE((2 * v) % 3, v, 0,
           STAGE_A((t + 2 < NKT ? t + 2 : NKT - 1), (2 * v + 2) % 3);
           STAGE_BP((q + 2 < 36 ? q + 2 : 35), (v + 2) % 3));
      TILE((2 * v + 1) % 3, v, 1,
           STAGE_A((t + 3 < NKT ? t + 3 : NKT - 1), (2 * v) % 3));
    }
  }

#undef STAGE_A
#undef STAGE_BP
#undef LDA
#undef LDB
#undef MFMA8
#undef HEAD
#undef TILE

  // Epilogue (verified): col = lane&31, row = (r&3)+8*(r>>2)+4*(lane>>5).
  // Nontemporal stores: output is a pure stream, keep it out of L3.
  int colb = n0 + wn * 64 + (lane & 31);
  int rb = wm * 128 + ((lane >> 5) << 2);
#pragma unroll
  for (int mt = 0; mt < 4; ++mt)
#pragma unroll
    for (int nt = 0; nt < 2; ++nt)
#pragma unroll
      for (int r = 0; r < 16; ++r) {
        int row = rb + mt * 32 + (r & 3) + ((r >> 2) << 3);
        __builtin_nontemporal_store(acc[mt][nt][r],
                                    &out[(size_t)row * NPTS + colb + nt * 32]);
      }
}

// Safety-net path if workspace is too small: direct conv, fp32.
__global__ __launch_bounds__(256) void naive_conv(const float* __restrict__ f,
                                                  const float* __restrict__ w,
                                                  const int* __restrict__ hi,
                                                  const int* __restrict__ wi,
                                                  float* __restrict__ out) {
  int idx = blockIdx.x * 256 + threadIdx.x;
  int n = idx & (NPTS - 1);
  int co = idx >> 16;
  int bh = hi[n] - 1;
  int bw = wi[n] - 1;
  float acc = 0.f;
  for (int ci = 0; ci < CIN; ++ci) {
    const float* fc = f + (size_t)ci * 262144;
    const float* wc = w + (size_t)co * 2304 + ci * 9;
#pragma unroll
    for (int t = 0; t < 9; ++t) {
      int y = bh + t / 3, x = bw + t % 3;
      float v = (y >= 0 && y < 512 && x >= 0 && x < 512) ? fc[y * 512 + x] : 0.f;
      acc += wc[t] * v;
    }
  }
  out[(size_t)co * NPTS + n] = acc;
}

extern "C" void kernel_launch(void* const* d_in, const int* in_sizes, int n_in,
                              void* d_out, int out_size, void* d_ws, size_t ws_size,
                              hipStream_t stream) {
  const float* feature = (const float*)d_in[0];
  const float* weight  = (const float*)d_in[1];
  const int* hidx      = (const int*)d_in[2];
  const int* widx      = (const int*)d_in[3];
  float* out           = (float*)d_out;

  const size_t FT_OFF = 2ull * 1024 * 1024;
  const size_t FT_BYTES = (size_t)NPIX * 256 * 2;   // ~135 MiB
  const size_t NEED = FT_OFF + FT_BYTES;

  if (ws_size >= NEED) {
    unsigned short* Abf = (unsigned short*)d_ws;    // 1.125 MiB
    unsigned short* Ft = (unsigned short*)((char*)d_ws + FT_OFF);
    prep_weight<<<(NKT * 8192) / 256, 256, 0, stream>>>(weight, Abf);
    border_zero<<<(2052 * 32 + 255) / 256, 256, 0, stream>>>(Ft);
    transpose_feat<<<262144 / 64, 256, 0, stream>>>(feature, Ft);
    gemm_gather<<<NPTS / 256, 512, 0, stream>>>(Abf, Ft, hidx, widx, out);
  } else {
    naive_conv<<<(COUT * NPTS) / 256, 256, 0, stream>>>(feature, weight, hidx, widx, out);
  }
}